// Round 5
// baseline (440.692 us; speedup 1.0000x reference)
//
#include <hip/hip_runtime.h>
#include <hip/hip_bf16.h>

typedef __attribute__((ext_vector_type(8))) short short8;
typedef __attribute__((ext_vector_type(4))) short short4v;
typedef __attribute__((ext_vector_type(4))) float f32x4;
typedef unsigned short u16;

// ---- bf16 helpers (bit-level, RNE) ----
__device__ inline float b2f(u16 u) {
    unsigned int i = ((unsigned int)u) << 16;
    float f; __builtin_memcpy(&f, &i, 4); return f;
}
__device__ inline u16 f2b(float f) {
    unsigned int i; __builtin_memcpy(&i, &f, 4);
    unsigned int r = (i + 0x7FFFu + ((i >> 16) & 1u)) >> 16;
    return (u16)r;
}

#define GLDS(g, l) __builtin_amdgcn_global_load_lds( \
    (const __attribute__((address_space(1))) void*)(g), \
    (__attribute__((address_space(3))) void*)(l), 16, 0, 0)

// ============================================================
// Phase 0: fp32 -> bf16 conversion (4 elements / thread)
// ============================================================
__global__ __launch_bounds__(256) void cvt_k(const float* __restrict__ src,
                                             u16* __restrict__ dst, int n4)
{
    const int i = blockIdx.x * blockDim.x + threadIdx.x;
    if (i < n4) {
        const f32x4 v = ((const f32x4*)src)[i];
        short4v o;
        o.x = (short)f2b(v.x); o.y = (short)f2b(v.y);
        o.z = (short)f2b(v.z); o.w = (short)f2b(v.w);
        ((short4v*)dst)[i] = o;
    }
}

// ============================================================
// Phase 0b: V0 transpose  V0T[b][j][n] = V0[b][n][j]  (fp32, 1 MB)
// ============================================================
__global__ __launch_bounds__(256) void vT_k(const float* __restrict__ V0,
                                            float* __restrict__ V0T)
{
    const int gid = blockIdx.x * 256 + threadIdx.x;   // 0..16383
    const int b = gid >> 9, j = (gid >> 6) & 7, n0 = (gid & 63) * 16;
    const float* src = V0 + (long)b * 8192 + (long)n0 * 8 + j;
    float* dst = V0T + (long)b * 8192 + (long)j * 1024 + n0;
#pragma unroll
    for (int i = 0; i < 16; i += 4) {
        f32x4 o = { src[(i + 0) * 8], src[(i + 1) * 8],
                    src[(i + 2) * 8], src[(i + 3) * 8] };
        *(f32x4*)(dst + i) = o;
    }
}

// ============================================================
// Phase 1a: fused GEMM  C = X · W^T, XOR-swizzled LDS (bank-conflict-free)
// Tiles: BM=128, BN=128, BK=64; 256 threads = 4 waves (2x2 of 64x64)
// ============================================================
__global__ __launch_bounds__(256) void gemm_kvq(
    const u16* __restrict__ X, const u16* __restrict__ Wbf,
    u16* __restrict__ Ko, u16* __restrict__ Vo, u16* __restrict__ Qo)
{
    __shared__ u16 As[128 * 64];
    __shared__ u16 Bs[128 * 64];

    const int bm = blockIdx.x;            // 0..127  (M tiles)
    const int bn = blockIdx.y;            // 0..23   (N tiles over 3072)
    const int widx = bn >> 3;
    const int n0 = (bn & 7) * 128;
    const u16* W = Wbf + (long)widx * 1048576;
    u16* O = (widx == 0) ? Ko : (widx == 1 ? Vo : Qo);

    const int tid = threadIdx.x;
    const int wave = tid >> 6;
    const int lane = tid & 63;

    const int srow = lane >> 3;                     // 0..7 row within 1KB chunk
    const int scol = ((lane & 7) ^ srow) * 8;       // swizzled source col block

    const int wm = (wave & 1) * 64;
    const int wn = (wave >> 1) * 64;
    const int qd = lane >> 4;
    const int ln = lane & 15;
    const int lx = ln & 7;                          // row&7 for swizzle

    f32x4 acc[4][4];
#pragma unroll
    for (int i = 0; i < 4; i++)
#pragma unroll
        for (int j = 0; j < 4; j++) acc[i][j] = (f32x4){0.f, 0.f, 0.f, 0.f};

    for (int k0 = 0; k0 < 1024; k0 += 64) {
        __syncthreads();  // prev-iter LDS reads done
#pragma unroll
        for (int c = 0; c < 4; c++) {
            const int chunk = wave * 4 + c;      // 0..15, 1KB each
            const int row = chunk * 8 + srow;    // tile row 0..127
            const u16* ga = X + (long)(bm * 128 + row) * 1024 + k0 + scol;
            GLDS(ga, &As[chunk * 512]);
            const u16* gb = W + (long)(n0 + row) * 1024 + k0 + scol;
            GLDS(gb, &Bs[chunk * 512]);
        }
        __syncthreads();  // drains vmcnt -> staged data visible
#pragma unroll
        for (int kk = 0; kk < 2; kk++) {
            short8 af[4], bf[4];
#pragma unroll
            for (int mt = 0; mt < 4; mt++)
                af[mt] = *(const short8*)&As[(wm + mt * 16 + ln) * 64 +
                                             (((kk * 4 + qd) ^ lx) * 8)];
#pragma unroll
            for (int nt = 0; nt < 4; nt++)
                bf[nt] = *(const short8*)&Bs[(wn + nt * 16 + ln) * 64 +
                                             (((kk * 4 + qd) ^ lx) * 8)];
#pragma unroll
            for (int mt = 0; mt < 4; mt++)
#pragma unroll
                for (int nt = 0; nt < 4; nt++)
                    acc[mt][nt] = __builtin_amdgcn_mfma_f32_16x16x32_bf16(
                        af[mt], bf[nt], acc[mt][nt], 0, 0, 0);
        }
    }

    // epilogue: C/D layout col=lane&15, row=quad*4+reg (verified m89/m91)
#pragma unroll
    for (int mt = 0; mt < 4; mt++) {
#pragma unroll
        for (int nt = 0; nt < 4; nt++) {
            const int r0 = bm * 128 + wm + mt * 16 + qd * 4;
            const int c = n0 + wn + nt * 16 + ln;
#pragma unroll
            for (int r = 0; r < 4; r++)
                O[(long)(r0 + r) * 1024 + c] = f2b(acc[mt][nt][r]);
        }
    }
}

// ============================================================
// Phase 1c: per-row scalars, 4 t's per block.
//   S[b][t][0..7]=Vtk_u*rn, [8..15]=k_r_u*rn, [16..23]=Vtq
// ============================================================
__global__ __launch_bounds__(256) void scal_k(
    const u16* __restrict__ K, const u16* __restrict__ Q,
    const float* __restrict__ V0T, const float* __restrict__ Wkr,
    float* __restrict__ S)
{
    const int b  = blockIdx.x & 31;
    const int t0 = (blockIdx.x >> 5) * 4;
    const int tid = threadIdx.x;
    const int j = tid & 7, c = tid >> 3;      // c: 0..31
    const int n0 = c * 32;

    f32x4 vv[8], ww[8];
    {
        const f32x4* vp = (const f32x4*)(V0T + (long)b * 8192 + (long)j * 1024 + n0);
        const f32x4* wp = (const f32x4*)(Wkr + (long)j * 1024 + n0);
#pragma unroll
        for (int i = 0; i < 8; i++) { vv[i] = vp[i]; ww[i] = wp[i]; }
    }

    float avk[4], akr[4], avq[4], ass[4];
#pragma unroll
    for (int dt = 0; dt < 4; dt++) { avk[dt] = akr[dt] = avq[dt] = ass[dt] = 0.f; }

#pragma unroll
    for (int dt = 0; dt < 4; dt++) {
        const long m = (long)(t0 + dt) * 32 + b;
        const short8* kp = (const short8*)(K + m * 1024 + n0);
        const short8* qp = (const short8*)(Q + m * 1024 + n0);
#pragma unroll
        for (int i = 0; i < 4; i++) {
            const short8 kb = kp[i], qb = qp[i];
#pragma unroll
            for (int e = 0; e < 8; e++) {
                const int idx = i * 8 + e;
                const float kv = b2f((u16)kb[e]);
                const float qv = b2f((u16)qb[e]);
                const float vj = vv[idx >> 2][idx & 3];
                const float wj = ww[idx >> 2][idx & 3];
                avk[dt] = fmaf(vj, kv, avk[dt]);
                akr[dt] = fmaf(wj, kv, akr[dt]);
                avq[dt] = fmaf(vj, qv, avq[dt]);
                ass[dt] = fmaf(kv, kv, ass[dt]);
            }
        }
    }

    __shared__ float red[4][4][3][8];   // [wave][dt][v][j]
    __shared__ float ssr[4][4];         // [wave][dt]
    const int wave = tid >> 6, lane = tid & 63;
#pragma unroll
    for (int dt = 0; dt < 4; dt++) {
        float a = avk[dt], k2 = akr[dt], q = avq[dt], s = ass[dt];
#pragma unroll
        for (int off = 8; off < 64; off <<= 1) {
            a  += __shfl_xor(a,  off, 64);
            k2 += __shfl_xor(k2, off, 64);
            q  += __shfl_xor(q,  off, 64);
            s  += __shfl_xor(s,  off, 64);
        }
        if (lane < 8) {
            red[wave][dt][0][lane] = a;
            red[wave][dt][1][lane] = k2;
            red[wave][dt][2][lane] = q;
        }
        if (lane == 0) ssr[wave][dt] = s;
    }
    __syncthreads();
    if (tid < 128) {
        const int dt = tid >> 5, rr = tid & 31;
        if (rr < 24) {
            const int v = rr >> 3, jj = rr & 7;
            float s = red[0][dt][v][jj] + red[1][dt][v][jj] +
                      red[2][dt][v][jj] + red[3][dt][v][jj];
            if (v != 2) {
                const float n2 = ssr[0][dt] + ssr[1][dt] + ssr[2][dt] + ssr[3][dt];
                s *= 1.0f / (sqrtf(n2) + 1e-6f);
            }
            S[((long)b * 512 + t0 + dt) * 32 + v * 8 + jj] = s;
        }
    }
}

// ============================================================
// Phase 2: the scan. One thread per (b, n); U[8] in registers.
// NO cross-lane ops in the recurrence (chain-critical). S[b] in LDS
// (depth-2 register pipeline); 16-step-deep global prefetch on V.
// 256 blocks x 128 thr = 1 block/CU, 2 waves/CU.
// ============================================================
__global__ __launch_bounds__(128) void scan_k(
    const u16* __restrict__ Vbuf, const float* __restrict__ S,
    const float* __restrict__ U0, float* __restrict__ outp,
    float* __restrict__ Ufin)
{
    __shared__ float Sl[512 * 32];  // 64 KB

    const int b = blockIdx.x >> 3;
    const int n = (blockIdx.x & 7) * 128 + threadIdx.x;

    // stage S[b] (coalesced, contiguous 64KB)
    {
        const f32x4* Sg = (const f32x4*)(S + (long)b * 16384);
        f32x4* Sd = (f32x4*)Sl;
        for (int i = threadIdx.x; i < 4096; i += 128) Sd[i] = Sg[i];
    }

    float U[8];
    {
        const float* u0 = U0 + ((long)b * 1024 + n) * 8;
#pragma unroll
        for (int j = 0; j < 8; j++) U[j] = u0[j];
    }

    const u16* vp0 = Vbuf + (long)b * 1024 + n;
    u16 vnx[16];
#pragma unroll
    for (int i = 0; i < 16; i++) vnx[i] = vp0[(long)i * 32768];

    __syncthreads();  // S staged

    // S pipeline prologue: sc = step 0, sn = step 1
    f32x4 sc[6], sn[6];
#pragma unroll
    for (int r = 0; r < 6; r++) sc[r] = *(const f32x4*)&Sl[r * 4];
#pragma unroll
    for (int r = 0; r < 6; r++) sn[r] = *(const f32x4*)&Sl[32 + r * 4];

    float* op = outp + (long)b * 1024 + n;

    for (int t0 = 0; t0 < 512; t0 += 16) {
        float vcur[16];
#pragma unroll
        for (int i = 0; i < 16; i++) vcur[i] = b2f(vnx[i]);
        const int tn = (t0 + 16 < 512) ? (t0 + 16) : t0;
#pragma unroll
        for (int i = 0; i < 16; i++) vnx[i] = vp0[(long)(tn + i) * 32768];

#pragma unroll
        for (int i = 0; i < 16; i++) {
            const int t = t0 + i;
            const int tf = (t + 2 < 512) ? (t + 2) : t;
            f32x4 sm[6];
#pragma unroll
            for (int r = 0; r < 6; r++) sm[r] = *(const f32x4*)&Sl[tf * 32 + r * 4];

            const f32x4 a0 = sc[0], a1 = sc[1], K0 = sc[2], K1 = sc[3],
                        Q0 = sc[4], Q1 = sc[5];
#pragma unroll
            for (int r = 0; r < 6; r++) { sc[r] = sn[r]; sn[r] = sm[r]; }

            // retrieved: 8-term dot, tree form for short chain
            const float p0 = fmaf(U[0], a0.x, U[1] * a0.y);
            const float p1 = fmaf(U[2], a0.z, U[3] * a0.w);
            const float p2 = fmaf(U[4], a1.x, U[5] * a1.y);
            const float p3 = fmaf(U[6], a1.z, U[7] * a1.w);
            const float retrieved = (p0 + p1) + (p2 + p3);
            const float delta = vcur[i] - retrieved;

            const float krj[8] = {K0.x, K0.y, K0.z, K0.w, K1.x, K1.y, K1.z, K1.w};
            const float vqj[8] = {Q0.x, Q0.y, Q0.z, Q0.w, Q1.x, Q1.y, Q1.z, Q1.w};

            float s0 = 0.f, s1 = 0.f, s2 = 0.f, s3 = 0.f;
#pragma unroll
            for (int j = 0; j < 8; j++) {
                const float x = fmaf(delta, krj[j], U[j]);
                const float e = __expf(2.0f * x);                               // v_exp_f32
                const float u = 1.0f - 2.0f * __builtin_amdgcn_rcpf(e + 1.0f);  // tanh
                U[j] = u;
                const float m = u * vqj[j];
                if ((j & 3) == 0) s0 += m; else if ((j & 3) == 1) s1 += m;
                else if ((j & 3) == 2) s2 += m; else s3 += m;
            }
            const float Sq = (s0 + s1) + (s2 + s3);
            const float sg = __builtin_amdgcn_rcpf(1.0f + __expf(-Sq));
            op[(long)t * 32768] = Sq * Sq * sg;  // Sq * silu(Sq)
        }
    }

    // U_final, fp32, two 16B vector stores
    float* uf = Ufin + ((long)b * 1024 + n) * 8;
    ((f32x4*)uf)[0] = (f32x4){U[0], U[1], U[2], U[3]};
    ((f32x4*)uf)[1] = (f32x4){U[4], U[5], U[6], U[7]};
}

// ============================================================
// V output = V0 (unchanged); 16B-wide fp32 copy (262144 floats)
// ============================================================
__global__ __launch_bounds__(256) void vcopy_k(const float* __restrict__ src,
                                               float* __restrict__ dst)
{
    const int i = blockIdx.x * blockDim.x + threadIdx.x;  // 0..65535
    ((f32x4*)dst)[i] = ((const f32x4*)src)[i];
}

// ============================================================
extern "C" void kernel_launch(void* const* d_in, const int* in_sizes, int n_in,
                              void* d_out, int out_size, void* d_ws, size_t ws_size,
                              hipStream_t stream)
{
    const float* x   = (const float*)d_in[0];   // [512,32,1024]
    const float* Wk  = (const float*)d_in[1];   // [1024,1024]
    const float* Wv  = (const float*)d_in[2];
    const float* Wq  = (const float*)d_in[3];
    const float* Wkr = (const float*)d_in[4];   // [8,1024]
    const float* U0  = (const float*)d_in[5];   // [32,1024,8]
    const float* V0  = (const float*)d_in[6];   // [32,1024,8]
    float* out = (float*)d_out;                 // output(16777216) + U_final(262144) + V(262144)

    char* ws = (char*)d_ws;
    u16*   Xbf = (u16*)(ws);                    // 33,554,432 B
    u16*   Wbf = (u16*)(ws + 33554432);         //  6,291,456 B (Wk|Wv|Wq stacked)
    u16*   Kb  = (u16*)(ws + 39845888);         // 33,554,432 B
    u16*   Vb  = (u16*)(ws + 73400320);         // 33,554,432 B
    u16*   Qb  = (u16*)(ws + 106954752);        // 33,554,432 B
    float* Sc  = (float*)(ws + 140509184);      //  2,097,152 B  (32 x 512 x 32 f32)
    float* V0T = (float*)(ws + 142606336);      //  1,048,576 B  (32 x 8 x 1024 f32)

    cvt_k<<<16384, 256, 0, stream>>>(x,  Xbf,               4194304);
    cvt_k<<<1024,  256, 0, stream>>>(Wk, Wbf,                262144);
    cvt_k<<<1024,  256, 0, stream>>>(Wv, Wbf + 1048576,      262144);
    cvt_k<<<1024,  256, 0, stream>>>(Wq, Wbf + 2097152,      262144);
    vT_k <<<64,    256, 0, stream>>>(V0, V0T);

    gemm_kvq<<<dim3(128, 24), 256, 0, stream>>>(Xbf, Wbf, Kb, Vb, Qb);
    scal_k  <<<4096, 256, 0, stream>>>(Kb, Qb, V0T, Wkr, Sc);
    scan_k  <<<256, 128, 0, stream>>>(Vb, Sc, U0, out, out + 16777216);
    vcopy_k <<<256, 256, 0, stream>>>(V0, out + 17039360);
}